// Round 7
// baseline (3161.585 us; speedup 1.0000x reference)
//
#include <hip/hip_runtime.h>

// ---------------------------------------------------------------------------
// GLIFR RSNN on MI355X — round 12: r11 with the S0 prefetch HOISTED TO THE
// STEP TOP. Single-variable fix of r11's identified regression mechanism.
//
// History:
//   r1 (PASSED, 11.75ms): 8 WGs/batch, cooperative, counter barrier.
//   r2/r3/r4/r7 (GHOST): cooperative launch + restructured sync -> kernel
//      never ran. Only r5's sync structure is proven under cooperative.
//   r5 (PASSED, 2290us recur): counter barrier; S0 load at step TOP, its
//      ~900cy HBM latency hidden under the spb-load RTT.
//   r6 (REGRESSED, 2465us): work before the wait at step top — wrong window.
//   r8 (DIED): VGPR math; single-CU-per-batch impossible. 8-WG split forced.
//   r9 (PASSED, 2590us): tagged data-is-flag at agent scope — 65536 pollers
//      congest the MALL. r10 (PASSED, 12.6ms): sc0 loads act device-scope.
//      MEMORY-PATH EXPERIMENTS CLOSED.
//   r11 (REGRESSED, 2600us): h1-in-window was right, but the S0 load moved
//      into the window put ~900cy of HBM latency SERIALLY before the S3
//      drain -> +1050cy/step exposed, −300cy h1 moved = +310us net. The
//      arithmetic of the regression matches the counter model.
//   r12 (this): r11 verbatim EXCEPT the S0[t] load issues at the step top
//      (after the spb loads issue, before the actS stores' waitcnt), carried
//      in 1 VGPR through the mid; the window does only [LDS store actO; S3;
//      fetch_add; h1 FMAs+reduce (~350cy, fills the spin idle); spin; S5].
//      Mid-section sheds h1's ~300cy vs r5; window has zero exposed memory
//      latency. Bit-identical arithmetic to r5/r11 (absmax 0.015625 twice
//      reproduced).
//
// NOTE (r2/r3 lesson, keep): fp32 S is EXACTLY 0.0 for strongly inhibited
// neurons (V ~ -1050 -> __expf overflow -> 20/inf = 0), identically in the
// jax reference. 0x00000000 output words are legitimate.
// ---------------------------------------------------------------------------

#define T_STEPS 1000
#define NB 32
#define N0 256
#define N1 512

// fp32 constants, folded exactly like the reference's python-float scalars
#define C_SYN_D 0.95f                      // 1 - DT*KSYN
#define C_SYN_I 0.05f                      // DT*KSYN
#define C_V_D   0.99f                      // 1 - DT*KM
#define C_KMR   0.0010604453870625663f     // DT*KM*R
#define C_TH    10.986122886681098f        // SIGMA_V * log((20-5)/5)
#define C_A0_D  0.99985f                   // 1 - DT*0.003
#define C_A0_I  (-0.459f)                  // -9.18*1.0*DT
#define C_A1_D  0.995f                     // 1 - DT*0.1
#define C_A1_I  (-9.947f)                  // -198.94*1.0*DT

__device__ __forceinline__ float glif_S(float V) {
  // 20 * sigmoid((V - TH)/10)
  return 20.0f / (1.0f + __expf((C_TH - V) * 0.1f));
}

// ---------------------------------------------------------------------------
// Kernel A: layer-0 scan (r5-verbatim, proven). grid = 128 x 64.
// ---------------------------------------------------------------------------
__global__ __launch_bounds__(64)
void layer0_scan(const float* __restrict__ x, float* __restrict__ S0) {
  const int g = blockIdx.x * 64 + threadIdx.x;
  float V = 0.f, a0 = 0.f, a1 = 0.f, Is = 0.f;
  float xb[8];
#pragma unroll
  for (int i = 0; i < 8; ++i) xb[i] = x[i * (NB * N0) + g];
#pragma unroll 1
  for (int tb = 0; tb < T_STEPS / 8; ++tb) {
#pragma unroll
    for (int u = 0; u < 8; ++u) {
      const int t = tb * 8 + u;
      const float xi = xb[u];
      const int tf = t + 8;
      if (tf < T_STEPS) xb[u] = x[tf * (NB * N0) + g];
      Is = fmaf(Is, C_SYN_D, C_SYN_I * xi);
      V  = fmaf(V, C_V_D, C_KMR * (Is + a0 + a1));
      const float S = glif_S(V);
      a0 = fmaf(a0, C_A0_D, C_A0_I * S);
      a1 = fmaf(a1, C_A1_D, C_A1_I * S);
      S0[t * (NB * N0) + g] = S;
    }
  }
}

// ---------------------------------------------------------------------------
// Kernel C: recurrence. grid = 256 x 256 (cooperative, r5-verbatim launch).
// wg = b*8 + s; m-slice = [s*64, s*64+64). tid = mg*16 + kc (r5-identical).
// Per step t:
//   [top]   issue spb_{t-1} loads; issue S0[t] load (v2, for t+1's h1);
//           stage spb into actS
//   S1      barrier
//   [mid]   h2 partial FMAs; h2 reduce; GLIF A (h1p) + GLIF B; stores
//   [wind]  actO <- v2 (LDS only); S3 drain; tid0 fetch_add;
//           h1 FMAs + reduce (fills spin idle); tid0 spin; S5 release
// ---------------------------------------------------------------------------
__global__ __launch_bounds__(256, 1)
void rsnn_recur(const float* __restrict__ W1, const float* __restrict__ Wr,
                const float* __restrict__ S0, float* __restrict__ out,
                unsigned* __restrict__ bar) {
  const int wg  = blockIdx.x;
  const int b   = wg >> 3;
  const int s   = wg & 7;
  const int tid = threadIdx.x;
  const int mg  = tid >> 4;
  const int kc  = tid & 15;
  const int mBase = s * 64 + mg * 4;

  __shared__ float actS[16 * 36];   // 512 spb values, padded (r5 layout)
  __shared__ float actO[16 * 20];   // 256 S0 values, padded (r5 layout)

  // --- one-time weight load into registers (r5-verbatim) ---
  float4 wr4[4][8];
  float4 w14[4][4];
#pragma unroll
  for (int i = 0; i < 4; ++i) {
    const float4* rw = (const float4*)(Wr + (size_t)(mBase + i) * N1 + kc * 32);
#pragma unroll
    for (int j = 0; j < 8; ++j) wr4[i][j] = rw[j];
    const float4* r1 = (const float4*)(W1 + (size_t)(mBase + i) * N0 + kc * 16);
#pragma unroll
    for (int j = 0; j < 4; ++j) w14[i][j] = r1[j];
  }

  float V[4]   = {0.f, 0.f, 0.f, 0.f};
  float A0v[4] = {0.f, 0.f, 0.f, 0.f};
  float A1v[4] = {0.f, 0.f, 0.f, 0.f};
  float Is[4]  = {0.f, 0.f, 0.f, 0.f};
  // h1 for step t, computed in step t-1's window. h1_0 = W1 @ 0 = 0.
  float h1p[4] = {0.f, 0.f, 0.f, 0.f};
  // one 128B cache line per batch's counter (r5)
  unsigned* cnt = bar + b * 32;

#pragma unroll 1
  for (int t = 0; t < T_STEPS; ++t) {
    // ---- [top] stage spb_{t-1}; issue S0[t] prefetch (v2) ----
    float v2;
    if (t == 0) {
      v2 = S0[b * N0 + tid];                 // S0[0] slab
      actS[(tid >> 5) * 36 + (tid & 31)] = 0.f;
      {
        const int k = tid + 256;
        actS[(k >> 5) * 36 + (k & 31)] = 0.f;
      }
    } else {
      const float* pS = out + ((size_t)(2 * t - 1) * NB + b) * N1;
      const float v0 = __hip_atomic_load(pS + tid,       __ATOMIC_RELAXED, __HIP_MEMORY_SCOPE_AGENT);
      const float v1 = __hip_atomic_load(pS + tid + 256, __ATOMIC_RELAXED, __HIP_MEMORY_SCOPE_AGENT);
      // issue S0[t] AFTER the spb loads (so their waitcnt can retire at
      // vmcnt(1)) but BEFORE the LDS stores; ~900cy latency hides under the
      // mid-section + drain. Used only in the window (and only if t<999;
      // S0[999] is in-bounds so no guard needed).
      v2 = S0[(size_t)t * (NB * N0) + b * N0 + tid];
      actS[(tid >> 5) * 36 + (tid & 31)] = v0;
      {
        const int k = tid + 256;
        actS[(k >> 5) * 36 + (k & 31)] = v1;
      }
    }
    __syncthreads();  // S1: actS visible

    // ---- h2 partial dots (weights from registers, acts from LDS) ----
    float h2a[4] = {0.f, 0.f, 0.f, 0.f};
    const float4* aS4 = (const float4*)actS;
#pragma unroll
    for (int j = 0; j < 8; ++j) {
      const float4 a = aS4[kc * 9 + j];
#pragma unroll
      for (int i = 0; i < 4; ++i) {
        h2a[i] = fmaf(wr4[i][j].x, a.x, h2a[i]);
        h2a[i] = fmaf(wr4[i][j].y, a.y, h2a[i]);
        h2a[i] = fmaf(wr4[i][j].z, a.z, h2a[i]);
        h2a[i] = fmaf(wr4[i][j].w, a.w, h2a[i]);
      }
    }
    // (post-FMA barrier removed — r11-proven: next actS overwrite is
    //  separated from these reads by BOTH S3 and S5.)

    // ---- reduce h2 across the 16 k-chunks (r5 masks, r5 order) ----
#pragma unroll
    for (int mask = 1; mask <= 8; mask <<= 1) {
#pragma unroll
      for (int i = 0; i < 4; ++i) {
        h2a[i] += __shfl_xor(h2a[i], mask, 64);
      }
    }

    // ---- owner lanes: GLIF A (h1p) then GLIF B (h2a) — r5-verbatim math --
    if (kc == 0) {
      float spa[4], spb[4];
#pragma unroll
      for (int i = 0; i < 4; ++i) {
        Is[i] = fmaf(Is[i], C_SYN_D, C_SYN_I * h1p[i]);
        V[i]  = fmaf(V[i], C_V_D, C_KMR * (Is[i] + A0v[i] + A1v[i]));
        const float Sa = glif_S(V[i]);
        A0v[i] = fmaf(A0v[i], C_A0_D, C_A0_I * Sa);
        A1v[i] = fmaf(A1v[i], C_A1_D, C_A1_I * Sa);
        spa[i] = Sa;
        Is[i] = fmaf(Is[i], C_SYN_D, C_SYN_I * h2a[i]);
        V[i]  = fmaf(V[i], C_V_D, C_KMR * (Is[i] + A0v[i] + A1v[i]));
        const float Sb = glif_S(V[i]);
        A0v[i] = fmaf(A0v[i], C_A0_D, C_A0_I * Sb);
        A1v[i] = fmaf(A1v[i], C_A1_D, C_A1_I * Sb);
        spb[i] = Sb;
      }
      float* outA = out + ((size_t)(2 * t) * NB + b) * N1 + mBase;
      *(float4*)outA = make_float4(spa[0], spa[1], spa[2], spa[3]);
      float* outB = out + ((size_t)(2 * t + 1) * NB + b) * N1 + mBase;
#pragma unroll
      for (int i = 0; i < 4; ++i)
        __hip_atomic_store(outB + i, spb[i], __ATOMIC_RELAXED, __HIP_MEMORY_SCOPE_AGENT);
    }

    // ---- [window] drain + arrive; h1_{t+1} fills the spin idle ----
    if (t < T_STEPS - 1) {
      // LDS-only store of the top-prefetched v2 (no memory latency here)
      actO[(tid >> 4) * 20 + (tid & 15)] = v2;
      __syncthreads();  // S3: compiler emits s_waitcnt vmcnt(0) before
                        // s_barrier: all lanes' write-through spb stores are
                        // globally visible before the flag increment below;
                        // also makes actO visible for the h1 FMAs.
      if (tid == 0) {
        __hip_atomic_fetch_add(cnt, 1u, __ATOMIC_RELAXED, __HIP_MEMORY_SCOPE_AGENT);
      }
      __builtin_amdgcn_sched_barrier(0);  // keep the add ahead of the h1 work

      // h1 partials + reduce for step t+1 — runs while the other 7 WGs'
      // adds propagate (the window r5 spent fully idle).
      float h1n[4] = {0.f, 0.f, 0.f, 0.f};
      const float4* aO4 = (const float4*)actO;
#pragma unroll
      for (int j = 0; j < 4; ++j) {
        const float4 a = aO4[kc * 5 + j];
#pragma unroll
        for (int i = 0; i < 4; ++i) {
          h1n[i] = fmaf(w14[i][j].x, a.x, h1n[i]);
          h1n[i] = fmaf(w14[i][j].y, a.y, h1n[i]);
          h1n[i] = fmaf(w14[i][j].z, a.z, h1n[i]);
          h1n[i] = fmaf(w14[i][j].w, a.w, h1n[i]);
        }
      }
#pragma unroll
      for (int mask = 1; mask <= 8; mask <<= 1) {
#pragma unroll
        for (int i = 0; i < 4; ++i) {
          h1n[i] += __shfl_xor(h1n[i], mask, 64);
        }
      }
#pragma unroll
      for (int i = 0; i < 4; ++i) h1p[i] = h1n[i];

      if (tid == 0) {
        const unsigned tgt = 8u * (unsigned)(t + 1);
        while (__hip_atomic_load(cnt, __ATOMIC_RELAXED, __HIP_MEMORY_SCOPE_AGENT) < tgt) {}
      }
      __syncthreads();  // S5: release — spb_t globally visible for step t+1
    }
  }
}

// ---------------------------------------------------------------------------
extern "C" void kernel_launch(void* const* d_in, const int* in_sizes, int n_in,
                              void* d_out, int out_size, void* d_ws, size_t ws_size,
                              hipStream_t stream) {
  const float* inputs = (const float*)d_in[0];   // [1000,32,1,256]
  const float* W1     = (const float*)d_in[1];   // [512,256]
  const float* Wr     = (const float*)d_in[2];   // [512,512]
  float* out = (float*)d_out;                    // [2000,32,1,512]

  float* S0 = (float*)d_ws;                                        // 32,768,000 B
  unsigned* bar = (unsigned*)((char*)d_ws +
                              (size_t)T_STEPS * NB * N0 * sizeof(float));

  // barrier counters must start at 0 every call (ws is re-poisoned to 0xAA);
  // 32 batches x 32 words = 4KB, one 128B line per batch.
  hipMemsetAsync(bar, 0, NB * 32 * sizeof(unsigned), stream);

  hipLaunchKernelGGL(layer0_scan, dim3((NB * N0) / 64), dim3(64), 0, stream,
                     inputs, S0);

  void* args[5];
  args[0] = (void*)&W1;
  args[1] = (void*)&Wr;
  args[2] = (void*)&S0;
  args[3] = (void*)&out;
  args[4] = (void*)&bar;
  // Cooperative launch (r5-verbatim): guarantees all 256 WGs (1/CU)
  // co-resident, so the per-batch spin barriers cannot deadlock.
  hipLaunchCooperativeKernel((const void*)rsnn_recur, dim3(256), dim3(256),
                             args, 0, stream);
}